// Round 2
// baseline (252.619 us; speedup 1.0000x reference)
//
#include <hip/hip_runtime.h>
#include <hip/hip_bf16.h>

typedef __attribute__((ext_vector_type(8))) short short8;   // 8 bf16 (4 VGPRs)
typedef __attribute__((ext_vector_type(4))) float f32x4;    // MFMA C/D

#define L_SEQ 4096
#define DM    1024
#define DA    128   // d_attn == d_mid

// fp32 -> bf16 round-to-nearest-even
__device__ __forceinline__ short f2bf(float f) {
    union { float f; unsigned u; } v; v.f = f;
    unsigned u = v.u;
    u += 0x7FFFu + ((u >> 16) & 1u);
    return (short)(u >> 16);
}

// ---------------------------------------------------------------------------
// Kernel 0: W transpose+convert.  W[m] fp32 [1024][128] -> WT[m] bf16 [128][1024]
// grid (32, 3), block 256.  Makes proj B-fragments contiguous 16B loads.
// ---------------------------------------------------------------------------
__global__ __launch_bounds__(256) void prep_w_kernel(
    const float* __restrict__ Wq, const float* __restrict__ Wk,
    const float* __restrict__ Wv, short* __restrict__ WT)
{
    const int m = blockIdx.y;
    const float* __restrict__ W = (m == 0) ? Wq : (m == 1) ? Wk : Wv;
    const int k0 = blockIdx.x * 32;
    __shared__ short Ts[DA * 33];   // [n][k] tile, pad 33 breaks bank stride
    const int t = threadIdx.x;
#pragma unroll
    for (int i = 0; i < 16; i++) {
        const int idx = i * 256 + t, kk = idx >> 7, nn = idx & 127;
        Ts[nn * 33 + kk] = f2bf(W[(size_t)(k0 + kk) * DA + nn]);
    }
    __syncthreads();
#pragma unroll
    for (int i = 0; i < 16; i++) {
        const int idx = i * 256 + t, nn = idx >> 5, kk = idx & 31;
        WT[((size_t)m * DA + nn) * DM + k0 + kk] = Ts[nn * 33 + kk];
    }
}

// ---------------------------------------------------------------------------
// Kernel 1: projection, split-K, barrier-free.  grid (64, 2, S), block 256.
// by==0: q = x@Wq (partial);  by==1: k = z@Wk AND v = z@Wv (z read once).
// Each wave: 16 rows x 128 cols over K-chunk 1024/S.  No LDS, no syncs.
// A prefetched one K-step ahead; partials fp32 to ws.
// ---------------------------------------------------------------------------
__global__ __launch_bounds__(256, 2) void proj_kernel(
    const float* __restrict__ x, const float* __restrict__ z,
    const short* __restrict__ WT, float* __restrict__ part)
{
    const int t = threadIdx.x;
    const int wave = t >> 6, lane = t & 63;
    const int l16 = lane & 15, quad = lane >> 4;
    const int isKV = blockIdx.y;
    const int S = gridDim.z, s = blockIdx.z;
    const int kbeg = s * (DM / S);
    const int ksteps = DM / (32 * S);
    const int row0w = blockIdx.x * 64 + wave * 16;

    const float* __restrict__ Am = isKV ? z : x;
    const float* ap = Am + (size_t)(row0w + l16) * DM + kbeg + quad * 8;
    const short* w1 = WT + (size_t)(isKV ? 1 : 0) * DA * DM;
    const short* w2 = WT + (size_t)2 * DA * DM;

    f32x4 acc1[8], acc2[8];
#pragma unroll
    for (int i = 0; i < 8; i++) {
        acc1[i] = (f32x4){0.f, 0.f, 0.f, 0.f};
        acc2[i] = (f32x4){0.f, 0.f, 0.f, 0.f};
    }

    f32x4 a0 = *(const f32x4*)ap;
    f32x4 a1 = *(const f32x4*)(ap + 4);

#pragma unroll 1
    for (int ks = 0; ks < ksteps; ks++) {
        // prefetch next A chunk (dup-load of current on last iter; L1 hit)
        const float* apn = ap + (size_t)((ks + 1 < ksteps) ? (ks + 1) : ks) * 32;
        f32x4 n0 = *(const f32x4*)apn;
        f32x4 n1 = *(const f32x4*)(apn + 4);

        short8 af;
        af[0] = f2bf(a0[0]); af[1] = f2bf(a0[1]); af[2] = f2bf(a0[2]); af[3] = f2bf(a0[3]);
        af[4] = f2bf(a1[0]); af[5] = f2bf(a1[1]); af[6] = f2bf(a1[2]); af[7] = f2bf(a1[3]);

        const int ko = kbeg + ks * 32 + quad * 8;
#pragma unroll
        for (int nt = 0; nt < 8; nt++) {
            short8 b = *(const short8*)&w1[(size_t)(nt * 16 + l16) * DM + ko];
            acc1[nt] = __builtin_amdgcn_mfma_f32_16x16x32_bf16(af, b, acc1[nt], 0, 0, 0);
        }
        if (isKV) {
#pragma unroll
            for (int nt = 0; nt < 8; nt++) {
                short8 b = *(const short8*)&w2[(size_t)(nt * 16 + l16) * DM + ko];
                acc2[nt] = __builtin_amdgcn_mfma_f32_16x16x32_bf16(af, b, acc2[nt], 0, 0, 0);
            }
        }
        a0 = n0; a1 = n1;
    }

    // epilogue: write fp32 partials (no bias yet).  C: row=quad*4+r, col=nt*16+l16
    const int m1 = isKV ? 1 : 0;
    float* p1 = part + (size_t)(s * 3 + m1) * L_SEQ * DA;
#pragma unroll
    for (int nt = 0; nt < 8; nt++) {
        const int col = nt * 16 + l16;
#pragma unroll
        for (int r = 0; r < 4; r++)
            p1[(size_t)(row0w + quad * 4 + r) * DA + col] = acc1[nt][r];
    }
    if (isKV) {
        float* p2 = part + (size_t)(s * 3 + 2) * L_SEQ * DA;
#pragma unroll
        for (int nt = 0; nt < 8; nt++) {
            const int col = nt * 16 + l16;
#pragma unroll
            for (int r = 0; r < 4; r++)
                p2[(size_t)(row0w + quad * 4 + r) * DA + col] = acc2[nt][r];
        }
    }
}

// ---------------------------------------------------------------------------
// Kernel 2: sum split-K partials + bias -> bf16 qb/kb, LDS-transposed vT.
// grid 128 (32 rows each), block 256.
// ---------------------------------------------------------------------------
__global__ __launch_bounds__(256) void finalize_kernel(
    const float* __restrict__ part, int S,
    const float* __restrict__ bq, const float* __restrict__ bk,
    const float* __restrict__ bv,
    short* __restrict__ qb, short* __restrict__ kb, short* __restrict__ vT)
{
    const int t = threadIdx.x;
    const int row0 = blockIdx.x * 32;
    __shared__ short Ts[DA * 34];   // v tile [col][rowlocal], pad 34

#pragma unroll 1
    for (int m = 0; m < 3; m++) {
        const float* __restrict__ bias = (m == 0) ? bq : (m == 1) ? bk : bv;
#pragma unroll
        for (int i = 0; i < 16; i++) {
            const int idx = i * 256 + t, r = idx >> 7, c = idx & 127;
            const int row = row0 + r;
            float v = bias[c];
            for (int s = 0; s < S; s++)
                v += part[((size_t)(s * 3 + m) * L_SEQ + row) * DA + c];
            const short o = f2bf(v);
            if (m == 0)      qb[(size_t)row * DA + c] = o;
            else if (m == 1) kb[(size_t)row * DA + c] = o;
            else             Ts[c * 34 + r] = o;
        }
    }
    __syncthreads();
#pragma unroll
    for (int i = 0; i < 16; i++) {
        const int idx = i * 256 + t, c = idx >> 5, r = idx & 31;
        vT[(size_t)c * L_SEQ + row0 + r] = Ts[c * 34 + r];
    }
}

// ---------------------------------------------------------------------------
// Kernel 3: flash attention, z split across blockIdx.y.  grid (256, Z), blk 256.
// Block owns 16 q rows; wave slice w16 = by*4+wave owns 1024/Z z-rows
// (niter tiles of 64).  Per-wave (m,l,O) partial -> ws; merged by kernel 4.
// ---------------------------------------------------------------------------
__global__ __launch_bounds__(256) void attn_kernel(
    const short* __restrict__ qb, const short* __restrict__ kb,
    const short* __restrict__ vT, float* __restrict__ OA,
    float* __restrict__ mA, float* __restrict__ lA, int niter, int W16)
{
    __shared__ __align__(16) short qs[16 * 136];
    __shared__ __align__(16) short Ps[4][16 * 68];   // stride 68: quads 8 banks apart

    const int t    = threadIdx.x;
    const int wave = t >> 6;
    const int lane = t & 63;
    const int l16  = lane & 15;
    const int quad = lane >> 4;
    const int qr0  = blockIdx.x * 16;
    const int w16  = blockIdx.y * 4 + wave;
    const int z0   = w16 * (niter * 64);

    {
        const int row = t >> 4, seg = t & 15;
        *(short8*)&qs[row * 136 + seg * 8] =
            *(const short8*)&qb[(size_t)(qr0 + row) * DA + seg * 8];
    }
    __syncthreads();

    short8 afrag[4];
#pragma unroll
    for (int ks = 0; ks < 4; ks++)
        afrag[ks] = *(const short8*)&qs[l16 * 136 + ks * 32 + quad * 8];

    f32x4 O[8];
#pragma unroll
    for (int i = 0; i < 8; i++) O[i] = (f32x4){0.f, 0.f, 0.f, 0.f};
    float m_i[4], l_i[4];
#pragma unroll
    for (int r = 0; r < 4; r++) { m_i[r] = -1e30f; l_i[r] = 0.f; }

    const float scale = 0.08838834764831845f;  // 1/sqrt(128)
    short* P = &Ps[wave][0];

#pragma unroll 1
    for (int it = 0; it < niter; it++) {
        const int zb = z0 + it * 64;

        f32x4 s[4];
#pragma unroll
        for (int nt = 0; nt < 4; nt++) s[nt] = (f32x4){0.f, 0.f, 0.f, 0.f};
#pragma unroll
        for (int nt = 0; nt < 4; nt++) {
            const short* kp = kb + (size_t)(zb + nt * 16 + l16) * DA + quad * 8;
#pragma unroll
            for (int ks = 0; ks < 4; ks++) {
                short8 b = *(const short8*)(kp + ks * 32);
                s[nt] = __builtin_amdgcn_mfma_f32_16x16x32_bf16(afrag[ks], b, s[nt], 0, 0, 0);
            }
        }

#pragma unroll
        for (int nt = 0; nt < 4; nt++)
#pragma unroll
            for (int r = 0; r < 4; r++) s[nt][r] *= scale;

        float rm[4];
#pragma unroll
        for (int r = 0; r < 4; r++)
            rm[r] = fmaxf(fmaxf(s[0][r], s[1][r]), fmaxf(s[2][r], s[3][r]));
#pragma unroll
        for (int off = 1; off < 16; off <<= 1)
#pragma unroll
            for (int r = 0; r < 4; r++)
                rm[r] = fmaxf(rm[r], __shfl_xor(rm[r], off));

        float mn[4], alpha[4], rs[4];
#pragma unroll
        for (int r = 0; r < 4; r++) {
            mn[r] = fmaxf(m_i[r], rm[r]);
            alpha[r] = __expf(m_i[r] - mn[r]);
            rs[r] = 0.f;
        }
#pragma unroll
        for (int nt = 0; nt < 4; nt++)
#pragma unroll
            for (int r = 0; r < 4; r++) {
                const float p = __expf(s[nt][r] - mn[r]);
                s[nt][r] = p;
                rs[r] += p;
            }
#pragma unroll
        for (int off = 1; off < 16; off <<= 1)
#pragma unroll
            for (int r = 0; r < 4; r++)
                rs[r] += __shfl_xor(rs[r], off);
#pragma unroll
        for (int r = 0; r < 4; r++) {
            l_i[r] = l_i[r] * alpha[r] + rs[r];
            m_i[r] = mn[r];
        }
#pragma unroll
        for (int nt = 0; nt < 8; nt++)
#pragma unroll
            for (int r = 0; r < 4; r++) O[nt][r] *= alpha[r];

#pragma unroll
        for (int nt = 0; nt < 4; nt++)
#pragma unroll
            for (int r = 0; r < 4; r++)
                P[(quad * 4 + r) * 68 + nt * 16 + l16] = f2bf(s[nt][r]);
        __threadfence_block();

#pragma unroll
        for (int ks2 = 0; ks2 < 2; ks2++) {
            short8 a2 = *(const short8*)&P[l16 * 68 + ks2 * 32 + quad * 8];
            const short* vp = vT + (size_t)l16 * L_SEQ + zb + ks2 * 32 + quad * 8;
#pragma unroll
            for (int nt = 0; nt < 8; nt++) {
                short8 b2 = *(const short8*)(vp + (size_t)(nt * 16) * L_SEQ);
                O[nt] = __builtin_amdgcn_mfma_f32_16x16x32_bf16(a2, b2, O[nt], 0, 0, 0);
            }
        }
    }

    // per-wave partial -> global
#pragma unroll
    for (int nt = 0; nt < 8; nt++)
#pragma unroll
        for (int r = 0; r < 4; r++) {
            const int row = qr0 + quad * 4 + r;
            OA[((size_t)row * W16 + w16) * DA + nt * 16 + l16] = O[nt][r];
        }
    if (l16 == 0) {
#pragma unroll
        for (int r = 0; r < 4; r++) {
            const int row = qr0 + quad * 4 + r;
            mA[(size_t)row * W16 + w16] = m_i[r];
            lA[(size_t)row * W16 + w16] = l_i[r];
        }
    }
}

// ---------------------------------------------------------------------------
// Kernel 4: merge W16 partials per q-row.  grid 128 (32 rows), block 256.
// ---------------------------------------------------------------------------
__global__ __launch_bounds__(256) void merge_kernel(
    const float* __restrict__ OA, const float* __restrict__ mA,
    const float* __restrict__ lA, float* __restrict__ out, int W16)
{
    const int t = threadIdx.x;
    const int row = blockIdx.x * 32 + (t >> 3);
    const int cg = (t & 7) * 16;

    float mf = -1e30f;
    for (int w = 0; w < W16; w++) mf = fmaxf(mf, mA[(size_t)row * W16 + w]);
    float lf = 0.f;
    for (int w = 0; w < W16; w++)
        lf += __expf(mA[(size_t)row * W16 + w] - mf) * lA[(size_t)row * W16 + w];

    f32x4 acc[4];
#pragma unroll
    for (int j = 0; j < 4; j++) acc[j] = (f32x4){0.f, 0.f, 0.f, 0.f};
    for (int w = 0; w < W16; w++) {
        const float e = __expf(mA[(size_t)row * W16 + w] - mf);
        const f32x4* op = (const f32x4*)&OA[((size_t)row * W16 + w) * DA + cg];
#pragma unroll
        for (int j = 0; j < 4; j++) acc[j] = acc[j] + op[j] * e;
    }
    const float inv = 1.f / lf;
    f32x4* dst = (f32x4*)&out[(size_t)row * DA + cg];
#pragma unroll
    for (int j = 0; j < 4; j++) dst[j] = acc[j] * inv;
}

// ---------------------------------------------------------------------------
extern "C" void kernel_launch(void* const* d_in, const int* in_sizes, int n_in,
                              void* d_out, int out_size, void* d_ws, size_t ws_size,
                              hipStream_t stream) {
    (void)in_sizes; (void)n_in; (void)out_size;
    const float* x  = (const float*)d_in[0];
    const float* z  = (const float*)d_in[1];
    const float* Wq = (const float*)d_in[2];
    const float* bq = (const float*)d_in[3];
    const float* Wk = (const float*)d_in[4];
    const float* bk = (const float*)d_in[5];
    const float* Wv = (const float*)d_in[6];
    const float* bv = (const float*)d_in[7];
    float* out = (float*)d_out;

    // ws layout (bytes):
    //   WT  @ 0        : 3*128*1024*2 = 786432
    //   qb  @ 786432   : 1 MB bf16 [4096][128]
    //   kb  @ +1 MB, vT @ +1 MB (vT is [128][4096])
    //   scratch @ 3932160: proj partials (S*6 MB) then, temporally disjoint,
    //                      attn partials OA/mA/lA (Z*8.5 MB) — aliased.
    short* WT = (short*)d_ws;
    short* qb = (short*)((char*)d_ws + 786432);
    short* kb = qb + (size_t)L_SEQ * DA;
    short* vT = kb + (size_t)L_SEQ * DA;
    char* scratch = (char*)d_ws + 3932160;
    const size_t avail = (ws_size > 3932160) ? ws_size - 3932160 : 0;

    int S, Z;
    if (avail >= 34078720ULL)      { S = 4; Z = 4; }
    else if (avail >= 25165824ULL) { S = 4; Z = 2; }
    else                           { S = 2; Z = 1; }
    const int W16 = 4 * Z;
    const int niter = L_SEQ / (Z * 4 * 64);   // z-tiles of 64 per wave

    float* part = (float*)scratch;
    float* OA = (float*)scratch;
    float* mA = (float*)(scratch + (size_t)L_SEQ * W16 * DA * 4);
    float* lA = mA + (size_t)L_SEQ * W16;

    prep_w_kernel<<<dim3(32, 3), 256, 0, stream>>>(Wq, Wk, Wv, WT);
    proj_kernel<<<dim3(64, 2, S), 256, 0, stream>>>(x, z, WT, part);
    finalize_kernel<<<128, 256, 0, stream>>>(part, S, bq, bk, bv, qb, kb, vT);
    attn_kernel<<<dim3(256, Z), 256, 0, stream>>>(qb, kb, vT, OA, mA, lA, niter, W16);
    merge_kernel<<<128, 256, 0, stream>>>(OA, mA, lA, out, W16);
}

// Round 3
// 180.241 us; speedup vs baseline: 1.4016x; 1.4016x over previous
//
#include <hip/hip_runtime.h>
#include <hip/hip_bf16.h>

typedef __attribute__((ext_vector_type(8))) short short8;   // 8 bf16 (4 VGPRs)
typedef __attribute__((ext_vector_type(4))) float f32x4;    // MFMA C/D

#define L_SEQ 4096
#define DM    1024
#define DA    128
#define PS    4      // proj split-K factor
#define AZ    4      // attn z-split (block-level partials)

// ws byte offsets (all 16B-aligned)
#define OFF_QB  786432      // after WTf (3*32*8*64 frags * 16B)
#define OFF_KF  1835008     // after qb (1 MB)
#define OFF_VF  2883584     // after kf (1 MB)
#define OFF_SCR 4063232     // after vf (1.125 MB): part (25.2MB) | OA+lA (8.45MB)

// fp32 -> bf16 round-to-nearest-even
__device__ __forceinline__ short f2bf(float f) {
    union { float f; unsigned u; } v; v.f = f;
    unsigned u = v.u;
    u += 0x7FFFu + ((u >> 16) & 1u);
    return (short)(u >> 16);
}

// ---------------------------------------------------------------------------
// Kernel 0: W -> fragment-major bf16.  WTf frag (m, kstep, nt, lane):
//   element j = W[kstep*32 + quad*8 + j][nt*16 + l16]
// grid (32, 3), block 256.  Proj B-loads become coalesced 1KB dwordx4.
// ---------------------------------------------------------------------------
__global__ __launch_bounds__(256) void prep_w_kernel(
    const float* __restrict__ Wq, const float* __restrict__ Wk,
    const float* __restrict__ Wv, short8* __restrict__ WTf)
{
    const int m = blockIdx.y, bx = blockIdx.x;
    const float* __restrict__ W = (m == 0) ? Wq : (m == 1) ? Wk : Wv;
    const int t = threadIdx.x;
#pragma unroll
    for (int i = 0; i < 2; i++) {
        const int u = i * 256 + t;
        const int nt = u >> 6, lane = u & 63, l16 = lane & 15, quad = lane >> 4;
        short8 fr;
#pragma unroll
        for (int j = 0; j < 8; j++)
            fr[j] = f2bf(W[(size_t)(bx * 32 + quad * 8 + j) * DA + nt * 16 + l16]);
        WTf[(((size_t)m * 32 + bx) * 8 + nt) * 64 + lane] = fr;
    }
}

// ---------------------------------------------------------------------------
// Kernel 1: projection, split-K, barrier-free.  grid (64, 2, PS), block 256.
// by==0: q partial; by==1: k and v partials fused (z read once).
// B-fragments: coalesced 1KB loads from WTf.  Partials fp32 -> part.
// ---------------------------------------------------------------------------
__global__ __launch_bounds__(256, 2) void proj_kernel(
    const float* __restrict__ x, const float* __restrict__ z,
    const short8* __restrict__ WTf, float* __restrict__ part)
{
    const int t = threadIdx.x;
    const int wave = t >> 6, lane = t & 63;
    const int l16 = lane & 15, quad = lane >> 4;
    const int isKV = blockIdx.y;
    const int s = blockIdx.z;
    const int kbeg = s * (DM / PS);
    const int ksteps = DM / (32 * PS);
    const int row0w = blockIdx.x * 64 + wave * 16;

    const float* __restrict__ Am = isKV ? z : x;
    const float* ap = Am + (size_t)(row0w + l16) * DM + kbeg + quad * 8;
    const int m1 = isKV ? 1 : 0;

    f32x4 acc1[8], acc2[8];
#pragma unroll
    for (int i = 0; i < 8; i++) {
        acc1[i] = (f32x4){0.f, 0.f, 0.f, 0.f};
        acc2[i] = (f32x4){0.f, 0.f, 0.f, 0.f};
    }

    f32x4 a0 = *(const f32x4*)ap;
    f32x4 a1 = *(const f32x4*)(ap + 4);

#pragma unroll 1
    for (int ks = 0; ks < ksteps; ks++) {
        const float* apn = ap + (size_t)((ks + 1 < ksteps) ? (ks + 1) : ks) * 32;
        f32x4 n0 = *(const f32x4*)apn;
        f32x4 n1 = *(const f32x4*)(apn + 4);

        short8 af;
        af[0] = f2bf(a0[0]); af[1] = f2bf(a0[1]); af[2] = f2bf(a0[2]); af[3] = f2bf(a0[3]);
        af[4] = f2bf(a1[0]); af[5] = f2bf(a1[1]); af[6] = f2bf(a1[2]); af[7] = f2bf(a1[3]);

        const int kidx = (kbeg >> 5) + ks;   // global kstep
#pragma unroll
        for (int nt = 0; nt < 8; nt++) {
            short8 b = WTf[(((size_t)m1 * 32 + kidx) * 8 + nt) * 64 + lane];
            acc1[nt] = __builtin_amdgcn_mfma_f32_16x16x32_bf16(af, b, acc1[nt], 0, 0, 0);
        }
        if (isKV) {
#pragma unroll
            for (int nt = 0; nt < 8; nt++) {
                short8 b = WTf[(((size_t)2 * 32 + kidx) * 8 + nt) * 64 + lane];
                acc2[nt] = __builtin_amdgcn_mfma_f32_16x16x32_bf16(af, b, acc2[nt], 0, 0, 0);
            }
        }
        a0 = n0; a1 = n1;
    }

    float* p1 = part + (size_t)(s * 3 + m1) * L_SEQ * DA;
#pragma unroll
    for (int nt = 0; nt < 8; nt++) {
        const int col = nt * 16 + l16;
#pragma unroll
        for (int r = 0; r < 4; r++)
            p1[(size_t)(row0w + quad * 4 + r) * DA + col] = acc1[nt][r];
    }
    if (isKV) {
        float* p2 = part + (size_t)(s * 3 + 2) * L_SEQ * DA;
#pragma unroll
        for (int nt = 0; nt < 8; nt++) {
            const int col = nt * 16 + l16;
#pragma unroll
            for (int r = 0; r < 4; r++)
                p2[(size_t)(row0w + quad * 4 + r) * DA + col] = acc2[nt][r];
        }
    }
}

// ---------------------------------------------------------------------------
// Kernel 2: split-K sum + bias -> qb row-major; K,V in fragment-major layouts.
// kf frag (zt, ks, nt, lane): elem j = k[zt*64 + nt*16 + l16][ks*32 + quad*8 + j]
// vf frag (zt, ks2, nt, lane): elem j = v[zt*64 + ks2*32 + quad*8 + j][nt*16 + l16]
//   nt==8 is the ones-column tile (row-sum trick): l16==0 -> 1.0, else 0.
// grid 128 (32 rows = one ks2 half-tile each), block 256.
// ---------------------------------------------------------------------------
__global__ __launch_bounds__(256) void finalize_kernel(
    const float* __restrict__ part,
    const float* __restrict__ bq, const float* __restrict__ bk,
    const float* __restrict__ bv,
    short* __restrict__ qb, short8* __restrict__ kf, short8* __restrict__ vf)
{
    const int t = threadIdx.x;
    const int row0 = blockIdx.x * 32;
    __shared__ short Ts[DA * 33];   // v tile [col][local row]

#pragma unroll 1
    for (int m = 0; m < 3; m++) {
        const float* __restrict__ bias = (m == 0) ? bq : (m == 1) ? bk : bv;
#pragma unroll
        for (int i = 0; i < 2; i++) {
            const int u = i * 256 + t;
            const int r = u >> 4, cg8 = u & 15;
            const int R = row0 + r, c0 = cg8 * 8;
            float vsum[8];
#pragma unroll
            for (int j = 0; j < 8; j++) vsum[j] = bias[c0 + j];
            for (int s = 0; s < PS; s++) {
                const float* p = &part[((size_t)(s * 3 + m) * L_SEQ + R) * DA + c0];
                f32x4 f0 = *(const f32x4*)p;
                f32x4 f1 = *(const f32x4*)(p + 4);
#pragma unroll
                for (int j = 0; j < 4; j++) { vsum[j] += f0[j]; vsum[4 + j] += f1[j]; }
            }
            short8 o;
#pragma unroll
            for (int j = 0; j < 8; j++) o[j] = f2bf(vsum[j]);

            if (m == 0) {
                *(short8*)&qb[(size_t)R * DA + c0] = o;
            } else if (m == 1) {
                const int zt = R >> 6, nt = (R >> 4) & 3, l16 = R & 15;
                const int ks = cg8 >> 2, quad = cg8 & 3;
                kf[(((size_t)zt * 4 + ks) * 4 + nt) * 64 + quad * 16 + l16] = o;
            } else {
#pragma unroll
                for (int j = 0; j < 8; j++) Ts[(c0 + j) * 33 + r] = o[j];
            }
        }
    }
    __syncthreads();

    // vf writes (incl. ones tile nt==8)
    const int zt = row0 >> 6, ks2 = (row0 >> 5) & 1;
#pragma unroll
    for (int i = 0; i < 3; i++) {
        const int u = i * 256 + t;
        if (u < 576) {
            const int nt = u >> 6, lane = u & 63, l16 = lane & 15, quad = lane >> 4;
            short8 fr;
            if (nt < 8) {
                const int col = nt * 16 + l16;
#pragma unroll
                for (int j = 0; j < 8; j++) fr[j] = Ts[col * 33 + quad * 8 + j];
            } else {
                const short one = (short)0x3F80;
#pragma unroll
                for (int j = 0; j < 8; j++) fr[j] = (l16 == 0) ? one : (short)0;
            }
            vf[(((size_t)zt * 2 + ks2) * 9 + nt) * 64 + lane] = fr;
        }
    }
}

// ---------------------------------------------------------------------------
// Kernel 3: flash attention, max-free softmax, zero cross-lane ops.
// grid (128, AZ), block 256 (4 waves).  Block owns 32 q-rows (2 tiles/wave);
// wave slice w16 = by*4 + wave owns 256 z-rows (4 tiles of 64).
// l (row sum) accumulated via the ones-column MFMA tile (nt==8).
// Per-block partial merged across waves via LDS atomicAdd -> OA[AZ partials].
// ---------------------------------------------------------------------------
__global__ __launch_bounds__(256) void attn_kernel(
    const short* __restrict__ qb, const short8* __restrict__ kf,
    const short8* __restrict__ vf, float* __restrict__ OA,
    float* __restrict__ lA)
{
    __shared__ __align__(16) short qs[32 * 136];
    __shared__ __align__(16) short Ps[4][2][16 * 68];
    __shared__ float Om[32 * DA];
    __shared__ float lsh[32];

    const int t    = threadIdx.x;
    const int wave = t >> 6;
    const int lane = t & 63;
    const int l16  = lane & 15;
    const int quad = lane >> 4;
    const int qr0  = blockIdx.x * 32;
    const int w16  = blockIdx.y * 4 + wave;

    {   // stage 32 q-rows + zero merge buffers
        const int row = t >> 3, seg = t & 7;
        *(short8*)&qs[row * 136 + seg * 16] =
            *(const short8*)&qb[(size_t)(qr0 + row) * DA + seg * 16];
        *(short8*)&qs[row * 136 + seg * 16 + 8] =
            *(const short8*)&qb[(size_t)(qr0 + row) * DA + seg * 16 + 8];
    }
#pragma unroll
    for (int i = 0; i < 16; i++) Om[i * 256 + t] = 0.f;
    if (t < 32) lsh[t] = 0.f;
    __syncthreads();

    short8 af[2][4];
#pragma unroll
    for (int at = 0; at < 2; at++)
#pragma unroll
        for (int ks = 0; ks < 4; ks++)
            af[at][ks] = *(const short8*)&qs[(at * 16 + l16) * 136 + ks * 32 + quad * 8];

    f32x4 O0[9], O1[9];
#pragma unroll
    for (int i = 0; i < 9; i++) {
        O0[i] = (f32x4){0.f, 0.f, 0.f, 0.f};
        O1[i] = (f32x4){0.f, 0.f, 0.f, 0.f};
    }

    const float C = 0.08838834764831845f;   // 1/sqrt(128)
    short* P0 = &Ps[wave][0][0];
    short* P1 = &Ps[wave][1][0];

#pragma unroll 1
    for (int it = 0; it < 4; it++) {
        const int zt = w16 * 4 + it;

        // ---- S = q @ k^T for both q-tiles, sharing each B-fragment ----
        f32x4 s0[4], s1[4];
#pragma unroll
        for (int nt = 0; nt < 4; nt++) {
            s0[nt] = (f32x4){0.f, 0.f, 0.f, 0.f};
            s1[nt] = (f32x4){0.f, 0.f, 0.f, 0.f};
        }
#pragma unroll
        for (int nt = 0; nt < 4; nt++)
#pragma unroll
            for (int ks = 0; ks < 4; ks++) {
                short8 b = kf[(((size_t)zt * 4 + ks) * 4 + nt) * 64 + lane];
                s0[nt] = __builtin_amdgcn_mfma_f32_16x16x32_bf16(af[0][ks], b, s0[nt], 0, 0, 0);
                s1[nt] = __builtin_amdgcn_mfma_f32_16x16x32_bf16(af[1][ks], b, s1[nt], 0, 0, 0);
            }

        // ---- max-free softmax numerator: p = exp(s/sqrt(d)); P -> LDS ----
#pragma unroll
        for (int nt = 0; nt < 4; nt++)
#pragma unroll
            for (int r = 0; r < 4; r++) {
                P0[(quad * 4 + r) * 68 + nt * 16 + l16] = f2bf(__expf(s0[nt][r] * C));
                P1[(quad * 4 + r) * 68 + nt * 16 + l16] = f2bf(__expf(s1[nt][r] * C));
            }
        __threadfence_block();

        // ---- O += P @ [V | 1]: 9th tile accumulates the row sums l ----
#pragma unroll
        for (int ks2 = 0; ks2 < 2; ks2++) {
            short8 a20 = *(const short8*)&P0[l16 * 68 + ks2 * 32 + quad * 8];
            short8 a21 = *(const short8*)&P1[l16 * 68 + ks2 * 32 + quad * 8];
#pragma unroll
            for (int nt = 0; nt < 9; nt++) {
                short8 b2 = vf[(((size_t)zt * 2 + ks2) * 9 + nt) * 64 + lane];
                O0[nt] = __builtin_amdgcn_mfma_f32_16x16x32_bf16(a20, b2, O0[nt], 0, 0, 0);
                O1[nt] = __builtin_amdgcn_mfma_f32_16x16x32_bf16(a21, b2, O1[nt], 0, 0, 0);
            }
        }
    }

    // ---- cross-wave merge (pure sums) via LDS atomics ----
#pragma unroll
    for (int nt = 0; nt < 8; nt++)
#pragma unroll
        for (int r = 0; r < 4; r++) {
            atomicAdd(&Om[(quad * 4 + r) * DA + nt * 16 + l16], O0[nt][r]);
            atomicAdd(&Om[(16 + quad * 4 + r) * DA + nt * 16 + l16], O1[nt][r]);
        }
    if (l16 == 0) {
#pragma unroll
        for (int r = 0; r < 4; r++) {
            atomicAdd(&lsh[quad * 4 + r], O0[8][r]);
            atomicAdd(&lsh[16 + quad * 4 + r], O1[8][r]);
        }
    }
    __syncthreads();

    {   // write block partial
        const int row = t >> 3, cs = (t & 7) * 16;
        float* dst = &OA[((size_t)blockIdx.y * L_SEQ + qr0 + row) * DA + cs];
        const float* src = &Om[row * DA + cs];
#pragma unroll
        for (int j = 0; j < 4; j++) ((f32x4*)dst)[j] = ((const f32x4*)src)[j];
        if (t < 32) lA[(size_t)blockIdx.y * L_SEQ + qr0 + t] = lsh[t];
    }
}

// ---------------------------------------------------------------------------
// Kernel 4: merge AZ partials: out = sum(OA) / sum(lA).  grid 256, block 256.
// ---------------------------------------------------------------------------
__global__ __launch_bounds__(256) void merge_kernel(
    const float* __restrict__ OA, const float* __restrict__ lA,
    float* __restrict__ out)
{
    const int t = threadIdx.x;
    const int row = blockIdx.x * 16 + (t >> 4);
    const int cg = (t & 15) * 8;

    f32x4 a0 = (f32x4){0.f, 0.f, 0.f, 0.f};
    f32x4 a1 = (f32x4){0.f, 0.f, 0.f, 0.f};
    float lsum = 0.f;
#pragma unroll
    for (int zz = 0; zz < AZ; zz++) {
        const float* p = &OA[((size_t)zz * L_SEQ + row) * DA + cg];
        a0 = a0 + *(const f32x4*)p;
        a1 = a1 + *(const f32x4*)(p + 4);
        lsum += lA[(size_t)zz * L_SEQ + row];
    }
    const float inv = 1.f / lsum;
    f32x4* dst = (f32x4*)&out[(size_t)row * DA + cg];
    dst[0] = a0 * inv;
    dst[1] = a1 * inv;
}

// ---------------------------------------------------------------------------
extern "C" void kernel_launch(void* const* d_in, const int* in_sizes, int n_in,
                              void* d_out, int out_size, void* d_ws, size_t ws_size,
                              hipStream_t stream) {
    (void)in_sizes; (void)n_in; (void)out_size; (void)ws_size;
    const float* x  = (const float*)d_in[0];
    const float* z  = (const float*)d_in[1];
    const float* Wq = (const float*)d_in[2];
    const float* bq = (const float*)d_in[3];
    const float* Wk = (const float*)d_in[4];
    const float* bk = (const float*)d_in[5];
    const float* Wv = (const float*)d_in[6];
    const float* bv = (const float*)d_in[7];
    float* out = (float*)d_out;

    short8* WTf = (short8*)d_ws;
    short*  qb  = (short*)((char*)d_ws + OFF_QB);
    short8* kf  = (short8*)((char*)d_ws + OFF_KF);
    short8* vf  = (short8*)((char*)d_ws + OFF_VF);
    char* scratch = (char*)d_ws + OFF_SCR;

    float* part = (float*)scratch;                       // PS*3*L*DA fp32 = 25.2 MB
    float* OA   = (float*)scratch;                       // AZ*L*DA fp32 = 8.4 MB (aliased, temporally disjoint)
    float* lA   = (float*)(scratch + (size_t)AZ * L_SEQ * DA * 4);

    prep_w_kernel<<<dim3(32, 3), 256, 0, stream>>>(Wq, Wk, Wv, WTf);
    proj_kernel<<<dim3(64, 2, PS), 256, 0, stream>>>(x, z, WTf, part);
    finalize_kernel<<<128, 256, 0, stream>>>(part, bq, bk, bv, qb, kf, vf);
    attn_kernel<<<dim3(128, AZ), 256, 0, stream>>>(qb, kf, vf, OA, lA);
    merge_kernel<<<256, 256, 0, stream>>>(OA, lA, out);
}

// Round 4
// 138.640 us; speedup vs baseline: 1.8221x; 1.3001x over previous
//
#include <hip/hip_runtime.h>
#include <hip/hip_bf16.h>

typedef __attribute__((ext_vector_type(8))) short short8;   // 8 bf16 (4 VGPRs)
typedef __attribute__((ext_vector_type(4))) float f32x4;    // MFMA C/D

#define L_SEQ 4096
#define DM    1024
#define DA    128
#define PS    2      // proj split-K factor
#define AZ    8      // attn z-split (block-level partials)

// ws byte offsets (all 16B-aligned)
#define OFF_QB  786432      // after WTf (3*32*8*64 frags * 16B)
#define OFF_KF  1835008     // after qb (1 MB)
#define OFF_VF  2883584     // after kf (1 MB)
#define OFF_SCR 4063232     // scratch: part (12.6MB) | OA+lA (16.9MB), aliased

// fp32 -> bf16 round-to-nearest-even
__device__ __forceinline__ short f2bf(float f) {
    union { float f; unsigned u; } v; v.f = f;
    unsigned u = v.u;
    u += 0x7FFFu + ((u >> 16) & 1u);
    return (short)(u >> 16);
}

// async global->LDS, 16B per lane: dest = wave-uniform lds base + lane*16
typedef const __attribute__((address_space(1))) void g_void_t;
typedef __attribute__((address_space(3))) void l_void_t;
__device__ __forceinline__ void g2lds16(const void* g, void* l) {
    __builtin_amdgcn_global_load_lds((g_void_t*)g, (l_void_t*)l, 16, 0, 0);
}

// ---------------------------------------------------------------------------
// Kernel 0: W -> fragment-major bf16.  WTf frag (m, kstep, nt, lane):
//   elem j = W[kstep*32 + quad*8 + j][nt*16 + l16].   grid (32,3), block 256.
// Coalesced f32x4 reads + LDS transpose.
// ---------------------------------------------------------------------------
__global__ __launch_bounds__(256) void prep_w_kernel(
    const float* __restrict__ Wq, const float* __restrict__ Wk,
    const float* __restrict__ Wv, short8* __restrict__ WTf)
{
    const int m = blockIdx.y, kidx = blockIdx.x;
    const float* __restrict__ W = (m == 0) ? Wq : (m == 1) ? Wk : Wv;
    __shared__ __align__(16) float Ws[32 * 132];
    const int t = threadIdx.x;
#pragma unroll
    for (int i = 0; i < 4; i++) {
        const int u = i * 256 + t;
        const int kk = u >> 5, n4 = (u & 31) * 4;
        *(f32x4*)&Ws[kk * 132 + n4] = *(const f32x4*)&W[(size_t)(kidx * 32 + kk) * DA + n4];
    }
    __syncthreads();
#pragma unroll
    for (int i = 0; i < 2; i++) {
        const int u = i * 256 + t;
        const int nt = u >> 6, lane = u & 63, l16 = lane & 15, quad = lane >> 4;
        short8 fr;
#pragma unroll
        for (int j = 0; j < 8; j++)
            fr[j] = f2bf(Ws[(quad * 8 + j) * 132 + nt * 16 + l16]);
        WTf[((size_t)(m * 32 + kidx) * 8 + nt) * 64 + lane] = fr;
    }
}

// ---------------------------------------------------------------------------
// Kernel 1: projection, split-K, W via LDS double-buffer (async staging).
// grid (64, 2, PS), block 256.  by==0: q partial; by==1: k+v fused.
// A per-lane global with prefetch depth 2.  Partials fp32 -> part.
// ---------------------------------------------------------------------------
__global__ __launch_bounds__(256, 1) void proj_kernel(
    const float* __restrict__ x, const float* __restrict__ z,
    const char* __restrict__ WTraw, float* __restrict__ part)
{
    __shared__ __align__(16) char wb[2][16384];

    const int t = threadIdx.x;
    const int wave = t >> 6, lane = t & 63;
    const int l16 = lane & 15, quad = lane >> 4;
    const int isKV = blockIdx.y;
    const int s = blockIdx.z;
    const int kbeg = s * (DM / PS);
    const int row0w = blockIdx.x * 64 + wave * 16;
    const int m1 = isKV ? 1 : 0;
    const int nbytes = isKV ? 16384 : 8192;
    const int ks0 = kbeg >> 5;

    const float* __restrict__ Am = isKV ? z : x;
    const float* ap = Am + (size_t)(row0w + l16) * DM + kbeg + quad * 8;

    f32x4 acc1[8], acc2[8];
#pragma unroll
    for (int i = 0; i < 8; i++) {
        acc1[i] = (f32x4){0.f, 0.f, 0.f, 0.f};
        acc2[i] = (f32x4){0.f, 0.f, 0.f, 0.f};
    }

    // stage W frags for global kstep kidx into wb[b]
    auto stage = [&](int kidx, int b) {
        const char* base1 = WTraw + (size_t)(m1 * 32 + kidx) * 8192;
        const char* base2 = WTraw + (size_t)(2 * 32 + kidx) * 8192;
#pragma unroll
        for (int i = 0; i < 4; i++) {
            const int off = i * 4096 + wave * 1024;
            if (off < nbytes) {
                const char* src = (off < 8192) ? (base1 + off) : (base2 + (off - 8192));
                g2lds16(src + lane * 16, &wb[b][off]);
            }
        }
    };

    // A pipeline: c = step ks, d = ks+1 (e fetched for ks+2 in-loop)
    f32x4 c0 = *(const f32x4*)ap,        c1 = *(const f32x4*)(ap + 4);
    f32x4 d0 = *(const f32x4*)(ap + 32), d1 = *(const f32x4*)(ap + 36);

    stage(ks0, 0);
    __syncthreads();

#pragma unroll 1
    for (int ks = 0; ks < 16; ks++) {
        const int b = ks & 1;
        if (ks + 1 < 16) stage(ks0 + ks + 1, b ^ 1);

        const int kpf = (ks + 2 < 16) ? ks + 2 : ks;
        f32x4 e0 = *(const f32x4*)(ap + kpf * 32);
        f32x4 e1 = *(const f32x4*)(ap + kpf * 32 + 4);

        short8 afr;
        afr[0] = f2bf(c0[0]); afr[1] = f2bf(c0[1]); afr[2] = f2bf(c0[2]); afr[3] = f2bf(c0[3]);
        afr[4] = f2bf(c1[0]); afr[5] = f2bf(c1[1]); afr[6] = f2bf(c1[2]); afr[7] = f2bf(c1[3]);

#pragma unroll
        for (int nt = 0; nt < 8; nt++) {
            short8 bfr = *(const short8*)&wb[b][(nt * 64 + lane) * 16];
            acc1[nt] = __builtin_amdgcn_mfma_f32_16x16x32_bf16(afr, bfr, acc1[nt], 0, 0, 0);
        }
        if (isKV) {
#pragma unroll
            for (int nt = 0; nt < 8; nt++) {
                short8 bfr = *(const short8*)&wb[b][8192 + (nt * 64 + lane) * 16];
                acc2[nt] = __builtin_amdgcn_mfma_f32_16x16x32_bf16(afr, bfr, acc2[nt], 0, 0, 0);
            }
        }
        __syncthreads();
        c0 = d0; c1 = d1; d0 = e0; d1 = e1;
    }

    float* p1 = part + (size_t)(s * 3 + m1) * L_SEQ * DA;
#pragma unroll
    for (int nt = 0; nt < 8; nt++) {
        const int col = nt * 16 + l16;
#pragma unroll
        for (int r = 0; r < 4; r++)
            p1[(size_t)(row0w + quad * 4 + r) * DA + col] = acc1[nt][r];
    }
    if (isKV) {
        float* p2 = part + (size_t)(s * 3 + 2) * L_SEQ * DA;
#pragma unroll
        for (int nt = 0; nt < 8; nt++) {
            const int col = nt * 16 + l16;
#pragma unroll
            for (int r = 0; r < 4; r++)
                p2[(size_t)(row0w + quad * 4 + r) * DA + col] = acc2[nt][r];
        }
    }
}

// ---------------------------------------------------------------------------
// Kernel 2: split-K sum + bias -> qb row-major; K,V granule-contiguous frags.
// kf granule (kg = z>>5): (kg, ks(4), nth(2), lane) -> 8192 B contiguous.
//   elem j = k[kg*32 + nth*16 + l16][ks*32 + quad*8 + j]
// vf granule (vg = z>>5): (vg, nt(9), lane) -> 9216 B contiguous.
//   elem j = v[vg*32 + quad*8 + j][nt*16 + l16]; nt==8 = ones column.
// grid 128 (32 rows = one granule each), block 256.
// ---------------------------------------------------------------------------
__global__ __launch_bounds__(256) void finalize_kernel(
    const float* __restrict__ part,
    const float* __restrict__ bq, const float* __restrict__ bk,
    const float* __restrict__ bv,
    short* __restrict__ qb, short8* __restrict__ kf, short8* __restrict__ vf)
{
    const int t = threadIdx.x;
    const int row0 = blockIdx.x * 32;
    __shared__ short Ts[DA * 33];   // v tile [col][local row]

#pragma unroll 1
    for (int m = 0; m < 3; m++) {
        const float* __restrict__ bias = (m == 0) ? bq : (m == 1) ? bk : bv;
#pragma unroll
        for (int i = 0; i < 2; i++) {
            const int u = i * 256 + t;
            const int r = u >> 4, cg8 = u & 15;
            const int R = row0 + r, c0 = cg8 * 8;
            float vsum[8];
#pragma unroll
            for (int j = 0; j < 8; j++) vsum[j] = bias[c0 + j];
            for (int s = 0; s < PS; s++) {
                const float* p = &part[((size_t)(s * 3 + m) * L_SEQ + R) * DA + c0];
                f32x4 f0 = *(const f32x4*)p;
                f32x4 f1 = *(const f32x4*)(p + 4);
#pragma unroll
                for (int j = 0; j < 4; j++) { vsum[j] += f0[j]; vsum[4 + j] += f1[j]; }
            }
            short8 o;
#pragma unroll
            for (int j = 0; j < 8; j++) o[j] = f2bf(vsum[j]);

            if (m == 0) {
                *(short8*)&qb[(size_t)R * DA + c0] = o;
            } else if (m == 1) {
                const int kg = R >> 5, nth = (R >> 4) & 1, l16 = R & 15;
                const int ks = cg8 >> 2, quad = cg8 & 3;
                kf[((size_t)(kg * 4 + ks) * 2 + nth) * 64 + quad * 16 + l16] = o;
            } else {
#pragma unroll
                for (int j = 0; j < 8; j++) Ts[(c0 + j) * 33 + r] = o[j];
            }
        }
    }
    __syncthreads();

    const int vg = blockIdx.x;   // one 32-row granule per block
#pragma unroll
    for (int i = 0; i < 3; i++) {
        const int u = i * 256 + t;
        if (u < 576) {
            const int nt = u >> 6, lane = u & 63, l16 = lane & 15, quad = lane >> 4;
            short8 fr;
            if (nt < 8) {
                const int col = nt * 16 + l16;
#pragma unroll
                for (int j = 0; j < 8; j++) fr[j] = Ts[col * 33 + quad * 8 + j];
            } else {
                const short one = (short)0x3F80;
#pragma unroll
                for (int j = 0; j < 8; j++) fr[j] = (l16 == 0) ? one : (short)0;
            }
            vf[((size_t)vg * 9 + nt) * 64 + lane] = fr;
        }
    }
}

// ---------------------------------------------------------------------------
// Kernel 3: flash attention (max-free softmax), K/V via LDS double-buffer.
// grid (32, AZ), block 256 (4 waves).  Wave owns 32 q-rows (2 tiles); all
// waves share each 32-z-row granule (16 granules per block).  Per-block
// z-partial (O, l) -> OA/lA; merged by kernel 4.
// ---------------------------------------------------------------------------
__global__ __launch_bounds__(256, 1) void attn_kernel(
    const short* __restrict__ qb, const char* __restrict__ kfg,
    const char* __restrict__ vfg, float* __restrict__ OA,
    float* __restrict__ lA)
{
    __shared__ __align__(16) char kv[2][17408];      // [buf][kf 8192 | vf 9216]
    __shared__ __align__(16) short Ps[4][2][16 * 40]; // per-wave P round-trip

    const int t    = threadIdx.x;
    const int wave = t >> 6;
    const int lane = t & 63;
    const int l16  = lane & 15;
    const int quad = lane >> 4;
    const int qr0  = blockIdx.x * 128;
    const int g0   = blockIdx.y * 16;   // first z-granule (32 rows each)

    auto stage = [&](int g, int b) {
        const char* kb_ = kfg + (size_t)(g0 + g) * 8192;
        const char* vb_ = vfg + (size_t)(g0 + g) * 9216;
#pragma unroll
        for (int i = 0; i < 5; i++) {
            const int off = i * 4096 + wave * 1024;
            if (off < 17408) {
                const char* src = (off < 8192) ? (kb_ + off) : (vb_ + (off - 8192));
                g2lds16(src + lane * 16, &kv[b][off]);
            }
        }
    };

    stage(0, 0);

    // q A-fragments direct from global (once; overlaps staging)
    short8 af[2][4];
    const short* qrow = qb + (size_t)(qr0 + wave * 32 + l16) * DA + quad * 8;
#pragma unroll
    for (int at = 0; at < 2; at++)
#pragma unroll
        for (int ks = 0; ks < 4; ks++)
            af[at][ks] = *(const short8*)(qrow + (size_t)at * 16 * DA + ks * 32);

    f32x4 O0[9], O1[9];
#pragma unroll
    for (int i = 0; i < 9; i++) {
        O0[i] = (f32x4){0.f, 0.f, 0.f, 0.f};
        O1[i] = (f32x4){0.f, 0.f, 0.f, 0.f};
    }

    const float C = 0.08838834764831845f;   // 1/sqrt(128)
    short* P0 = &Ps[wave][0][0];
    short* P1 = &Ps[wave][1][0];

    __syncthreads();   // buf0 ready

#pragma unroll 1
    for (int g = 0; g < 16; g++) {
        const int b = g & 1;
        if (g + 1 < 16) stage(g + 1, b ^ 1);   // async; drains at end-of-iter barrier

        const char* kb_ = &kv[b][0];
        const char* vb_ = &kv[b][8192];

        // ---- S = q @ k^T over this 32-z granule (2 nth halves) ----
        f32x4 s0[2], s1[2];
#pragma unroll
        for (int nh = 0; nh < 2; nh++) {
            s0[nh] = (f32x4){0.f, 0.f, 0.f, 0.f};
            s1[nh] = (f32x4){0.f, 0.f, 0.f, 0.f};
        }
#pragma unroll
        for (int nh = 0; nh < 2; nh++)
#pragma unroll
            for (int ks = 0; ks < 4; ks++) {
                short8 bfr = *(const short8*)(kb_ + ((ks * 2 + nh) * 64 + lane) * 16);
                s0[nh] = __builtin_amdgcn_mfma_f32_16x16x32_bf16(af[0][ks], bfr, s0[nh], 0, 0, 0);
                s1[nh] = __builtin_amdgcn_mfma_f32_16x16x32_bf16(af[1][ks], bfr, s1[nh], 0, 0, 0);
            }

        // ---- p = exp(s*C) -> P (wave-private LDS, A-operand layout) ----
#pragma unroll
        for (int nh = 0; nh < 2; nh++)
#pragma unroll
            for (int r = 0; r < 4; r++) {
                P0[(quad * 4 + r) * 40 + nh * 16 + l16] = f2bf(__expf(s0[nh][r] * C));
                P1[(quad * 4 + r) * 40 + nh * 16 + l16] = f2bf(__expf(s1[nh][r] * C));
            }
        // wave-local DS RAW: wait LDS writes only (NOT vmcnt - keep prefetch async)
        asm volatile("" ::: "memory");
        __builtin_amdgcn_s_waitcnt(0xc07f);   // lgkmcnt(0), vmcnt/expcnt untouched
        asm volatile("" ::: "memory");

        // ---- O += P @ [V | 1] (K=32, one A-frag per q-tile) ----
        short8 a20 = *(const short8*)&P0[l16 * 40 + quad * 8];
        short8 a21 = *(const short8*)&P1[l16 * 40 + quad * 8];
#pragma unroll
        for (int nt = 0; nt < 9; nt++) {
            short8 b2 = *(const short8*)(vb_ + (nt * 64 + lane) * 16);
            O0[nt] = __builtin_amdgcn_mfma_f32_16x16x32_bf16(a20, b2, O0[nt], 0, 0, 0);
            O1[nt] = __builtin_amdgcn_mfma_f32_16x16x32_bf16(a21, b2, O1[nt], 0, 0, 0);
        }
        __syncthreads();   // staging for g+1 drained; all waves done with buf b
    }

    // ---- per-wave partial -> global (rows are wave-exclusive) ----
    const int rw = qr0 + wave * 32;
    float* Ob = OA + (size_t)blockIdx.y * L_SEQ * DA;
#pragma unroll
    for (int nt = 0; nt < 8; nt++)
#pragma unroll
        for (int r = 0; r < 4; r++) {
            Ob[(size_t)(rw + quad * 4 + r) * DA + nt * 16 + l16] = O0[nt][r];
            Ob[(size_t)(rw + 16 + quad * 4 + r) * DA + nt * 16 + l16] = O1[nt][r];
        }
    if (l16 == 0) {
        float* lb = lA + (size_t)blockIdx.y * L_SEQ;
#pragma unroll
        for (int r = 0; r < 4; r++) {
            lb[rw + quad * 4 + r] = O0[8][r];
            lb[rw + 16 + quad * 4 + r] = O1[8][r];
        }
    }
}

// ---------------------------------------------------------------------------
// Kernel 4: merge AZ partials: out = sum(OA) / sum(lA).  grid 256, block 256.
// ---------------------------------------------------------------------------
__global__ __launch_bounds__(256) void merge_kernel(
    const float* __restrict__ OA, const float* __restrict__ lA,
    float* __restrict__ out)
{
    const int t = threadIdx.x;
    const int row = blockIdx.x * 16 + (t >> 4);
    const int cg = (t & 15) * 8;

    f32x4 a0 = (f32x4){0.f, 0.f, 0.f, 0.f};
    f32x4 a1 = (f32x4){0.f, 0.f, 0.f, 0.f};
    float lsum = 0.f;
#pragma unroll
    for (int zz = 0; zz < AZ; zz++) {
        const float* p = &OA[((size_t)zz * L_SEQ + row) * DA + cg];
        a0 = a0 + *(const f32x4*)p;
        a1 = a1 + *(const f32x4*)(p + 4);
        lsum += lA[(size_t)zz * L_SEQ + row];
    }
    const float inv = 1.f / lsum;
    f32x4* dst = (f32x4*)&out[(size_t)row * DA + cg];
    dst[0] = a0 * inv;
    dst[1] = a1 * inv;
}

// ---------------------------------------------------------------------------
extern "C" void kernel_launch(void* const* d_in, const int* in_sizes, int n_in,
                              void* d_out, int out_size, void* d_ws, size_t ws_size,
                              hipStream_t stream) {
    (void)in_sizes; (void)n_in; (void)out_size; (void)ws_size;
    const float* x  = (const float*)d_in[0];
    const float* z  = (const float*)d_in[1];
    const float* Wq = (const float*)d_in[2];
    const float* bq = (const float*)d_in[3];
    const float* Wk = (const float*)d_in[4];
    const float* bk = (const float*)d_in[5];
    const float* Wv = (const float*)d_in[6];
    const float* bv = (const float*)d_in[7];
    float* out = (float*)d_out;

    short8* WTf = (short8*)d_ws;
    short*  qb  = (short*)((char*)d_ws + OFF_QB);
    short8* kf  = (short8*)((char*)d_ws + OFF_KF);
    short8* vf  = (short8*)((char*)d_ws + OFF_VF);
    char* scratch = (char*)d_ws + OFF_SCR;

    float* part = (float*)scratch;                       // PS*3*L*DA fp32 = 12.6 MB
    float* OA   = (float*)scratch;                       // AZ*L*DA fp32 = 16.8 MB (aliased, temporally disjoint)
    float* lA   = (float*)(scratch + (size_t)AZ * L_SEQ * DA * 4);

    prep_w_kernel<<<dim3(32, 3), 256, 0, stream>>>(Wq, Wk, Wv, WTf);
    proj_kernel<<<dim3(64, 2, PS), 256, 0, stream>>>(x, z, (const char*)WTf, part);
    finalize_kernel<<<128, 256, 0, stream>>>(part, bq, bk, bv, qb, kf, vf);
    attn_kernel<<<dim3(32, AZ), 256, 0, stream>>>(qb, (const char*)kf, (const char*)vf, OA, lA);
    merge_kernel<<<256, 256, 0, stream>>>(OA, lA, out);
}

// Round 5
// 130.716 us; speedup vs baseline: 1.9326x; 1.0606x over previous
//
#include <hip/hip_runtime.h>
#include <hip/hip_bf16.h>

typedef __attribute__((ext_vector_type(8))) short short8;   // 8 bf16 (4 VGPRs)
typedef __attribute__((ext_vector_type(4))) float f32x4;    // MFMA C/D

#define L_SEQ 4096
#define DM    1024
#define DA    128
#define AZ    8      // attn z-split (block-level partials)

// ws byte offsets (16B-aligned)
#define OFF_QB  786432      // after WTf (3*32*8*64 frags * 16B = 768 KB)
#define OFF_KF  1835008     // after qb (1 MB)
#define OFF_VF  2883584     // after kf (1 MB)
#define OFF_OA  4063232     // after vf (1.125 MB): OA 16.78 MB, then lA 128 KB

// fp32 -> bf16 round-to-nearest-even
__device__ __forceinline__ short f2bf(float f) {
    union { float f; unsigned u; } v; v.f = f;
    unsigned u = v.u;
    u += 0x7FFFu + ((u >> 16) & 1u);
    return (short)(u >> 16);
}

// async global->LDS, 16B per lane: dest = wave-uniform lds base + lane*16
typedef const __attribute__((address_space(1))) void g_void_t;
typedef __attribute__((address_space(3))) void l_void_t;
__device__ __forceinline__ void g2lds16(const void* g, void* l) {
    __builtin_amdgcn_global_load_lds((g_void_t*)g, (l_void_t*)l, 16, 0, 0);
}

// ---------------------------------------------------------------------------
// Kernel 0: W -> fragment-major bf16.  WTf frag (m, kstep, nt, lane):
//   elem j = W[kstep*32 + quad*8 + j][nt*16 + l16].   grid (32,3), block 256.
// ---------------------------------------------------------------------------
__global__ __launch_bounds__(256) void prep_w_kernel(
    const float* __restrict__ Wq, const float* __restrict__ Wk,
    const float* __restrict__ Wv, short8* __restrict__ WTf)
{
    const int m = blockIdx.y, kidx = blockIdx.x;
    const float* __restrict__ W = (m == 0) ? Wq : (m == 1) ? Wk : Wv;
    __shared__ __align__(16) float Ws[32 * 132];
    const int t = threadIdx.x;
#pragma unroll
    for (int i = 0; i < 4; i++) {
        const int u = i * 256 + t;
        const int kk = u >> 5, n4 = (u & 31) * 4;
        *(f32x4*)&Ws[kk * 132 + n4] = *(const f32x4*)&W[(size_t)(kidx * 32 + kk) * DA + n4];
    }
    __syncthreads();
#pragma unroll
    for (int i = 0; i < 2; i++) {
        const int u = i * 256 + t;
        const int nt = u >> 6, lane = u & 63, l16 = lane & 15, quad = lane >> 4;
        short8 fr;
#pragma unroll
        for (int j = 0; j < 8; j++)
            fr[j] = f2bf(Ws[(quad * 8 + j) * 132 + nt * 16 + l16]);
        WTf[((size_t)(m * 32 + kidx) * 8 + nt) * 64 + lane] = fr;
    }
}

// ---------------------------------------------------------------------------
// Kernel 1: fused QKV.  grid (128, 2), block 256.  by==0: q from x; by==1:
// k AND v from z (z read once).  Block owns 32 rows x full K=1024, BK=64
// (16 dbuf iterations).  Wave -> (mtile = w>>1, nhalf = w&1).  Epilogue
// writes FINAL outputs (bias added): qb row-major; k/v relaid to granule
// fragment layouts via LDS transpose (reusing staging buffer).
//   kf granule kg=z>>5: frag(kg,ks,nth,lane) elem j = k[kg*32+nth*16+l16][ks*32+quad*8+j]
//   vf granule vg=z>>5: frag(vg,nt,lane)     elem j = v[vg*32+quad*8+j][nt*16+l16]
//     nt==8 = ones column (row-sum trick).
// ---------------------------------------------------------------------------
__global__ __launch_bounds__(256, 1) void qkv_kernel(
    const float* __restrict__ x, const float* __restrict__ z,
    const char* __restrict__ WTraw,
    const float* __restrict__ bq, const float* __restrict__ bk,
    const float* __restrict__ bv,
    short* __restrict__ qb, short8* __restrict__ kf, short8* __restrict__ vf)
{
    __shared__ __align__(16) char smem[2][32768];

    const int t = threadIdx.x;
    const int wave = t >> 6, lane = t & 63;
    const int l16 = lane & 15, quad = lane >> 4;
    const int mtile = wave >> 1, nhalf = wave & 1;
    const int isKV = blockIdx.y;
    const int m1 = isKV ? 1 : 0;
    const int row0 = blockIdx.x * 32;
    const int nbytes = isKV ? 32768 : 16384;

    const float* __restrict__ Am = isKV ? z : x;
    const float* ap = Am + (size_t)(row0 + mtile * 16 + l16) * DM + quad * 8;

    f32x4 acc1[4], acc2[4];
#pragma unroll
    for (int i = 0; i < 4; i++) {
        acc1[i] = (f32x4){0.f, 0.f, 0.f, 0.f};
        acc2[i] = (f32x4){0.f, 0.f, 0.f, 0.f};
    }

    // stage W frags for BK=64 iteration it2 into smem[b]:
    //   [m1 kstep even 8K][m1 kstep odd 8K][(kv) Wv even 8K][Wv odd 8K]
    auto stage = [&](int it2, int b) {
        const char* base1 = WTraw + (size_t)(m1 * 32 + it2 * 2) * 8192;
        const char* base2 = WTraw + (size_t)(2 * 32 + it2 * 2) * 8192;
#pragma unroll
        for (int i = 0; i < 8; i++) {
            const int off = i * 4096 + wave * 1024;
            if (off < nbytes) {
                const char* src = (off < 16384) ? (base1 + off) : (base2 + (off - 16384));
                g2lds16(src + lane * 16, &smem[b][off]);
            }
        }
    };

    // A pipeline: 4 f32x4 per iteration (two 32-k substeps), prefetch depth 2
    f32x4 cur[4], nxt[4];
#pragma unroll
    for (int j = 0; j < 2; j++) {
        cur[j * 2]     = *(const f32x4*)(ap + j * 32);
        cur[j * 2 + 1] = *(const f32x4*)(ap + j * 32 + 4);
        nxt[j * 2]     = *(const f32x4*)(ap + 64 + j * 32);
        nxt[j * 2 + 1] = *(const f32x4*)(ap + 64 + j * 32 + 4);
    }

    stage(0, 0);
    __syncthreads();

#pragma unroll 1
    for (int it = 0; it < 16; it++) {
        const int b = it & 1;
        if (it + 1 < 16) stage(it + 1, b ^ 1);

        const int ipf = (it + 2 < 16) ? it + 2 : it;
        f32x4 fut[4];
#pragma unroll
        for (int j = 0; j < 2; j++) {
            fut[j * 2]     = *(const f32x4*)(ap + ipf * 64 + j * 32);
            fut[j * 2 + 1] = *(const f32x4*)(ap + ipf * 64 + j * 32 + 4);
        }

#pragma unroll
        for (int ss = 0; ss < 2; ss++) {
            short8 afr;
#pragma unroll
            for (int j = 0; j < 4; j++) {
                afr[j]     = f2bf(cur[ss * 2][j]);
                afr[4 + j] = f2bf(cur[ss * 2 + 1][j]);
            }
#pragma unroll
            for (int ntl = 0; ntl < 4; ntl++) {
                short8 bfr = *(const short8*)&smem[b][ss * 8192 + ((nhalf * 4 + ntl) * 64 + lane) * 16];
                acc1[ntl] = __builtin_amdgcn_mfma_f32_16x16x32_bf16(afr, bfr, acc1[ntl], 0, 0, 0);
            }
            if (isKV) {
#pragma unroll
                for (int ntl = 0; ntl < 4; ntl++) {
                    short8 bfr = *(const short8*)&smem[b][16384 + ss * 8192 + ((nhalf * 4 + ntl) * 64 + lane) * 16];
                    acc2[ntl] = __builtin_amdgcn_mfma_f32_16x16x32_bf16(afr, bfr, acc2[ntl], 0, 0, 0);
                }
            }
        }
        __syncthreads();
#pragma unroll
        for (int j = 0; j < 4; j++) { cur[j] = nxt[j]; nxt[j] = fut[j]; }
    }

    // ---- epilogue.  C layout: row = mtile*16 + quad*4 + r, col = nhalf*64 + ntl*16 + l16
    if (!isKV) {
#pragma unroll
        for (int ntl = 0; ntl < 4; ntl++) {
            const int col = nhalf * 64 + ntl * 16 + l16;
            const float bb = bq[col];
#pragma unroll
            for (int r = 0; r < 4; r++)
                qb[(size_t)(row0 + mtile * 16 + quad * 4 + r) * DA + col] =
                    f2bf(acc1[ntl][r] + bb);
        }
        return;
    }

    // k/v: C-frags -> LDS tiles [32][132] (k at smem 0, v at smem +16384)
    short* kT = (short*)&smem[0][0];
    short* vT = (short*)&smem[0][16384];
#pragma unroll
    for (int ntl = 0; ntl < 4; ntl++) {
        const int col = nhalf * 64 + ntl * 16 + l16;
        const float bbk = bk[col], bbv = bv[col];
#pragma unroll
        for (int r = 0; r < 4; r++) {
            const int rl = mtile * 16 + quad * 4 + r;
            kT[rl * 132 + col] = f2bf(acc1[ntl][r] + bbk);
            vT[rl * 132 + col] = f2bf(acc2[ntl][r] + bbv);
        }
    }
    __syncthreads();

    const int kg = blockIdx.x;   // this block's 32 rows = one granule
    // kf: 512 frags
#pragma unroll
    for (int i = 0; i < 2; i++) {
        const int f = i * 256 + t;
        const int ks = f >> 7, nth = (f >> 6) & 1, ln = f & 63;
        const int lf = ln & 15, qf = ln >> 4;
        short8 fr;
#pragma unroll
        for (int j = 0; j < 8; j++)
            fr[j] = kT[(nth * 16 + lf) * 132 + ks * 32 + qf * 8 + j];
        kf[((size_t)(kg * 4 + ks) * 2 + nth) * 64 + ln] = fr;
    }
    // vf: 576 frags (incl. ones tile nt==8)
#pragma unroll
    for (int i = 0; i < 3; i++) {
        const int f = i * 256 + t;
        if (f < 576) {
            const int nt = f >> 6, ln = f & 63;
            const int lf = ln & 15, qf = ln >> 4;
            short8 fr;
            if (nt < 8) {
#pragma unroll
                for (int j = 0; j < 8; j++)
                    fr[j] = vT[(qf * 8 + j) * 132 + nt * 16 + lf];
            } else {
                const short one = (short)0x3F80;
#pragma unroll
                for (int j = 0; j < 8; j++) fr[j] = (lf == 0) ? one : (short)0;
            }
            vf[((size_t)kg * 9 + nt) * 64 + ln] = fr;
        }
    }
}

// ---------------------------------------------------------------------------
// Kernel 2: flash attention (max-free softmax), K/V via LDS double-buffer.
// grid (64, AZ), block 256 (4 waves), 2 blocks/CU.  Wave owns 16 q-rows;
// all waves share each 32-z-row granule (16 granules per block).
// ---------------------------------------------------------------------------
__global__ __launch_bounds__(256, 2) void attn_kernel(
    const short* __restrict__ qb, const char* __restrict__ kfg,
    const char* __restrict__ vfg, float* __restrict__ OA,
    float* __restrict__ lA)
{
    __shared__ __align__(16) char kv[2][17408];       // [buf][kf 8192 | vf 9216]
    __shared__ __align__(16) short Ps[4][16 * 40];    // per-wave P round-trip

    const int t    = threadIdx.x;
    const int wave = t >> 6;
    const int lane = t & 63;
    const int l16  = lane & 15;
    const int quad = lane >> 4;
    const int qr0  = blockIdx.x * 64;
    const int g0   = blockIdx.y * 16;   // first z-granule (32 rows each)

    auto stage = [&](int g, int b) {
        const char* kb_ = kfg + (size_t)(g0 + g) * 8192;
        const char* vb_ = vfg + (size_t)(g0 + g) * 9216;
#pragma unroll
        for (int i = 0; i < 5; i++) {
            const int off = i * 4096 + wave * 1024;
            if (off < 17408) {
                const char* src = (off < 8192) ? (kb_ + off) : (vb_ + (off - 8192));
                g2lds16(src + lane * 16, &kv[b][off]);
            }
        }
    };

    stage(0, 0);

    // q A-fragments direct from global (once; overlaps staging)
    short8 af[4];
    const short* qrow = qb + (size_t)(qr0 + wave * 16 + l16) * DA + quad * 8;
#pragma unroll
    for (int ks = 0; ks < 4; ks++)
        af[ks] = *(const short8*)(qrow + ks * 32);

    f32x4 O[9];
#pragma unroll
    for (int i = 0; i < 9; i++) O[i] = (f32x4){0.f, 0.f, 0.f, 0.f};

    const float C = 0.08838834764831845f;   // 1/sqrt(128)
    short* P = &Ps[wave][0];

    __syncthreads();   // buf0 ready

#pragma unroll 1
    for (int g = 0; g < 16; g++) {
        const int b = g & 1;
        if (g + 1 < 16) stage(g + 1, b ^ 1);   // async; drains at end-of-iter barrier

        const char* kb_ = &kv[b][0];
        const char* vb_ = &kv[b][8192];

        // ---- S = q @ k^T over this 32-z granule ----
        f32x4 s0[2];
#pragma unroll
        for (int nh = 0; nh < 2; nh++) s0[nh] = (f32x4){0.f, 0.f, 0.f, 0.f};
#pragma unroll
        for (int nh = 0; nh < 2; nh++)
#pragma unroll
            for (int ks = 0; ks < 4; ks++) {
                short8 bfr = *(const short8*)(kb_ + ((ks * 2 + nh) * 64 + lane) * 16);
                s0[nh] = __builtin_amdgcn_mfma_f32_16x16x32_bf16(af[ks], bfr, s0[nh], 0, 0, 0);
            }

        // ---- p = exp(s*C) -> P (wave-private LDS, A-operand layout) ----
#pragma unroll
        for (int nh = 0; nh < 2; nh++)
#pragma unroll
            for (int r = 0; r < 4; r++)
                P[(quad * 4 + r) * 40 + nh * 16 + l16] = f2bf(__expf(s0[nh][r] * C));
        // wave-local DS RAW: wait LDS writes only (keep async prefetch in flight)
        asm volatile("" ::: "memory");
        __builtin_amdgcn_s_waitcnt(0xc07f);   // lgkmcnt(0) only
        asm volatile("" ::: "memory");

        // ---- O += P @ [V | 1] (K=32, single A-frag) ----
        short8 a2 = *(const short8*)&P[l16 * 40 + quad * 8];
#pragma unroll
        for (int nt = 0; nt < 9; nt++) {
            short8 b2 = *(const short8*)(vb_ + (nt * 64 + lane) * 16);
            O[nt] = __builtin_amdgcn_mfma_f32_16x16x32_bf16(a2, b2, O[nt], 0, 0, 0);
        }
        __syncthreads();   // staging for g+1 drained; all waves done with buf b
    }

    // ---- per-wave partial -> global (rows wave-exclusive) ----
    const int rw = qr0 + wave * 16;
    float* Ob = OA + (size_t)blockIdx.y * L_SEQ * DA;
#pragma unroll
    for (int nt = 0; nt < 8; nt++)
#pragma unroll
        for (int r = 0; r < 4; r++)
            Ob[(size_t)(rw + quad * 4 + r) * DA + nt * 16 + l16] = O[nt][r];
    if (l16 == 0) {
        float* lb = lA + (size_t)blockIdx.y * L_SEQ;
#pragma unroll
        for (int r = 0; r < 4; r++)
            lb[rw + quad * 4 + r] = O[8][r];
    }
}

// ---------------------------------------------------------------------------
// Kernel 3: merge AZ partials: out = sum(OA) / sum(lA).  grid 256, block 256.
// ---------------------------------------------------------------------------
__global__ __launch_bounds__(256) void merge_kernel(
    const float* __restrict__ OA, const float* __restrict__ lA,
    float* __restrict__ out)
{
    const int t = threadIdx.x;
    const int row = blockIdx.x * 16 + (t >> 4);
    const int cg = (t & 15) * 8;

    f32x4 a0 = (f32x4){0.f, 0.f, 0.f, 0.f};
    f32x4 a1 = (f32x4){0.f, 0.f, 0.f, 0.f};
    float lsum = 0.f;
#pragma unroll
    for (int zz = 0; zz < AZ; zz++) {
        const float* p = &OA[((size_t)zz * L_SEQ + row) * DA + cg];
        a0 = a0 + *(const f32x4*)p;
        a1 = a1 + *(const f32x4*)(p + 4);
        lsum += lA[(size_t)zz * L_SEQ + row];
    }
    const float inv = 1.f / lsum;
    f32x4* dst = (f32x4*)&out[(size_t)row * DA + cg];
    dst[0] = a0 * inv;
    dst[1] = a1 * inv;
}

// ---------------------------------------------------------------------------
extern "C" void kernel_launch(void* const* d_in, const int* in_sizes, int n_in,
                              void* d_out, int out_size, void* d_ws, size_t ws_size,
                              hipStream_t stream) {
    (void)in_sizes; (void)n_in; (void)out_size; (void)ws_size;
    const float* x  = (const float*)d_in[0];
    const float* z  = (const float*)d_in[1];
    const float* Wq = (const float*)d_in[2];
    const float* bq = (const float*)d_in[3];
    const float* Wk = (const float*)d_in[4];
    const float* bk = (const float*)d_in[5];
    const float* Wv = (const float*)d_in[6];
    const float* bv = (const float*)d_in[7];
    float* out = (float*)d_out;

    short8* WTf = (short8*)d_ws;
    short*  qb  = (short*)((char*)d_ws + OFF_QB);
    short8* kf  = (short8*)((char*)d_ws + OFF_KF);
    short8* vf  = (short8*)((char*)d_ws + OFF_VF);
    float*  OA  = (float*)((char*)d_ws + OFF_OA);            // AZ*L*DA fp32
    float*  lA  = (float*)((char*)d_ws + OFF_OA + (size_t)AZ * L_SEQ * DA * 4);

    prep_w_kernel<<<dim3(32, 3), 256, 0, stream>>>(Wq, Wk, Wv, WTf);
    qkv_kernel<<<dim3(128, 2), 256, 0, stream>>>(x, z, (const char*)WTf,
                                                 bq, bk, bv, qb, kf, vf);
    attn_kernel<<<dim3(64, AZ), 256, 0, stream>>>(qb, (const char*)kf,
                                                  (const char*)vf, OA, lA);
    merge_kernel<<<256, 256, 0, stream>>>(OA, lA, out);
}